// Round 13
// baseline (498.150 us; speedup 1.0000x reference)
//
#include <hip/hip_runtime.h>
#include <math.h>

// GraphCNN v13: v12 + conv0 folded into k_eembed (W0 in LDS, shfl-broadcast
//  conv; VGPR ~30 so gather occupancy preserved — unlike v9/k_eefc). h0 buffer
//  and k_conv launch deleted. hj stores made non-temporal (read only by pool).
//  Assumes N <= 131072 (NB <= 512), E < 2^24, N < 2^17.

#define EPB 4096  // edges per binning block

__device__ __forceinline__ void nt_store4(float* p, float4 v) {
  __builtin_nontemporal_store(v.x, p + 0);
  __builtin_nontemporal_store(v.y, p + 1);
  __builtin_nontemporal_store(v.z, p + 2);
  __builtin_nontemporal_store(v.w, p + 3);
}

// ------- node embed: e0[n][j] = sum_k x[n][k] w[k][j] + b[j]  (K=128) -------
__global__ __launch_bounds__(256) void k_embed(
    const float* __restrict__ x, const float* __restrict__ w,
    const float* __restrict__ b, float* __restrict__ out, int N) {
  __shared__ __align__(16) float rl[64 * 128];
  const int t = threadIdx.x;
  const int j = t & 63;
  const int wv = t >> 6;
  const int base = blockIdx.x * 64;
  float wr[128];
#pragma unroll
  for (int k = 0; k < 128; ++k) wr[k] = w[k * 64 + j];
  const float bj = b[j];
#pragma unroll
  for (int it = 0; it < 8; ++it) {
    int lin = (t + it * 256) * 4;
    int r = lin >> 7, c = lin & 127;
    int row = base + r;
    float4 v = (row < N) ? *(const float4*)&x[(size_t)row * 128 + c]
                         : make_float4(0.f, 0.f, 0.f, 0.f);
    *(float4*)&rl[lin] = v;
  }
  __syncthreads();
  for (int r = wv; r < 64; r += 4) {
    int row = base + r;
    if (row >= N) break;
    float acc = bj;
#pragma unroll
    for (int k4 = 0; k4 < 32; ++k4) {
      float4 a = *(const float4*)&rl[r * 128 + k4 * 4];
      acc = fmaf(a.x, wr[k4 * 4 + 0], acc);
      acc = fmaf(a.y, wr[k4 * 4 + 1], acc);
      acc = fmaf(a.z, wr[k4 * 4 + 2], acc);
      acc = fmaf(a.w, wr[k4 * 4 + 3], acc);
    }
    out[(size_t)row * 64 + j] = acc;
  }
}

// ------- per-block bucket histograms, bucket-major: matT[bucket*NBLK + blk] -------
__global__ __launch_bounds__(256) void k_hist(
    const int* __restrict__ erow, const int* __restrict__ ecol,
    int* __restrict__ matTc, int* __restrict__ matTr, int E, int NB, int NBLK) {
  __shared__ int hc[512], hr[512];
  int b = blockIdx.x, t = threadIdx.x;
  for (int i = t; i < NB; i += 256) { hc[i] = 0; hr[i] = 0; }
  __syncthreads();
  int e0 = b * EPB;
#pragma unroll
  for (int q = 0; q < 16; ++q) {
    int e = e0 + q * 256 + t;
    if (e < E) {
      atomicAdd(&hc[ecol[e] >> 8], 1);
      atomicAdd(&hr[erow[e] >> 8], 1);
    }
  }
  __syncthreads();
  for (int i = t; i < NB; i += 256) {
    matTc[(size_t)i * NBLK + b] = hc[i];
    matTr[(size_t)i * NBLK + b] = hr[i];
  }
}

// ------- per-bucket scan over blocks; grid = 2*NB (c then r) -------
__global__ __launch_bounds__(256) void kBscan(
    int* __restrict__ matTc, int* __restrict__ matTr,
    int* __restrict__ totc, int* __restrict__ totr, int NB, int NBLK) {
  __shared__ int sc[256];
  int bi = blockIdx.x, t = threadIdx.x;
  int side = (bi >= NB) ? 1 : 0;
  int i = bi - side * NB;
  int* row = (side ? matTr : matTc) + (size_t)i * NBLK;
  int* tot = side ? totr : totc;
  int e0 = (2 * t < NBLK) ? row[2 * t] : 0;
  int e1 = (2 * t + 1 < NBLK) ? row[2 * t + 1] : 0;
  int s = e0 + e1;
  sc[t] = s;
  __syncthreads();
  for (int d = 1; d < 256; d <<= 1) {
    int x = (t >= d) ? sc[t - d] : 0;
    __syncthreads();
    sc[t] += x;
    __syncthreads();
  }
  int excl = sc[t] - s;
  if (2 * t < NBLK) row[2 * t] = excl;
  if (2 * t + 1 < NBLK) row[2 * t + 1] = excl + e0;
  if (t == 255) tot[i] = sc[255];
}

// ------- exclusive scan of bucket totals -> starts; grid = 2 -------
__global__ __launch_bounds__(512) void kB2(
    const int* __restrict__ totc, const int* __restrict__ totr,
    int* __restrict__ startc, int* __restrict__ startr, int NB) {
  __shared__ int sc[512];
  int t = threadIdx.x;
  const int* tot = blockIdx.x ? totr : totc;
  int* start = blockIdx.x ? startr : startc;
  int s = (t < NB) ? tot[t] : 0;
  sc[t] = s;
  __syncthreads();
  for (int d = 1; d < 512; d <<= 1) {
    int x = (t >= d) ? sc[t - d] : 0;
    __syncthreads();
    sc[t] += x;
    __syncthreads();
  }
  if (t < NB) start[t] = sc[t] - s;
}

// ------- scatter into bucket regions; LDS cursors, no global atomics -------
__global__ __launch_bounds__(256) void k_scat(
    const int* __restrict__ erow, const int* __restrict__ ecol,
    const int* __restrict__ matTc, const int* __restrict__ matTr,
    const int* __restrict__ startc, const int* __restrict__ startr,
    unsigned long long* __restrict__ tmpc, unsigned int* __restrict__ tmpr,
    int E, int NB, int NBLK) {
  __shared__ int curc[512], curr[512];
  int b = blockIdx.x, t = threadIdx.x;
  for (int i = t; i < NB; i += 256) {
    curc[i] = startc[i] + matTc[(size_t)i * NBLK + b];
    curr[i] = startr[i] + matTr[(size_t)i * NBLK + b];
  }
  __syncthreads();
  int e0 = b * EPB;
#pragma unroll
  for (int q = 0; q < 16; ++q) {
    int e = e0 + q * 256 + t;
    if (e < E) {
      int r = erow[e], c = ecol[e];
      int pc = atomicAdd(&curc[c >> 8], 1);
      tmpc[pc] = (unsigned long long)(c & 255) |
                 ((unsigned long long)r << 8) |
                 ((unsigned long long)e << 25);
      int pr = atomicAdd(&curr[r >> 8], 1);
      tmpr[pr] = ((unsigned int)e << 8) | (unsigned int)(r & 255);
    }
  }
}

// ------- merged: per-bucket degree + CSR offset + placement; grid = 2*NB -------
__global__ __launch_bounds__(256) void k_bplace(
    const unsigned long long* __restrict__ tmpc,
    const unsigned int* __restrict__ tmpr,
    const int* __restrict__ startc, const int* __restrict__ startr,
    const int* __restrict__ totc, const int* __restrict__ totr,
    int* __restrict__ indeg, int* __restrict__ outdeg,
    int* __restrict__ offc, int* __restrict__ offr,
    int* __restrict__ srcl, int* __restrict__ eidc, int* __restrict__ eidr,
    int N, int NB) {
  __shared__ int h[256], sc[256];
  int bi = blockIdx.x, t = threadIdx.x;
  int side = (bi >= NB) ? 1 : 0;
  int b = bi - side * NB;
  h[t] = 0;
  __syncthreads();
  int bstart = side ? startr[b] : startc[b];
  int cnt = side ? totr[b] : totc[b];
  if (side) {
    for (int i = t; i < cnt; i += 256)
      atomicAdd(&h[(int)(tmpr[bstart + i] & 255)], 1);
  } else {
    for (int i = t; i < cnt; i += 256)
      atomicAdd(&h[(int)(tmpc[bstart + i] & 255)], 1);
  }
  __syncthreads();
  int s = h[t];
  sc[t] = s;
  __syncthreads();
  for (int d = 1; d < 256; d <<= 1) {
    int x = (t >= d) ? sc[t - d] : 0;
    __syncthreads();
    sc[t] += x;
    __syncthreads();
  }
  int n = (b << 8) + t;
  int myoff = bstart + sc[t] - s;
  if (n < N) {
    if (side) { outdeg[n] = s; offr[n] = myoff; }
    else      { indeg[n] = s;  offc[n] = myoff; }
  }
  h[t] = myoff;  // reuse as place cursor
  __syncthreads();
  if (side) {
    for (int i = t; i < cnt; i += 256) {
      unsigned int v = tmpr[bstart + i];   // L2-warm
      int p = atomicAdd(&h[(int)(v & 255)], 1);
      eidr[p] = (int)(v >> 8);
    }
  } else {
    for (int i = t; i < cnt; i += 256) {
      unsigned long long v = tmpc[bstart + i];
      int p = atomicAdd(&h[(int)(v & 255)], 1);
      srcl[p] = (int)((v >> 8) & 0x1FFFF);
      eidc[p] = (int)(v >> 25);
    }
  }
}

// ------- fused edge embed + conv0: dual ea-gather (32-deep) + 16->64 GEMM,
//         then conv0 via shfl-broadcast + W0 in LDS (VGPR stays low) -------
__global__ __launch_bounds__(256) void k_eembed(
    const float* __restrict__ e0, const float* __restrict__ ea,
    const int* __restrict__ eidc, const int* __restrict__ eidr,
    const int* __restrict__ offc, const int* __restrict__ indeg,
    const int* __restrict__ offr, const int* __restrict__ outdeg,
    const float* __restrict__ ew, const float* __restrict__ eb,
    const float* __restrict__ w0, float* __restrict__ dis,
    float* __restrict__ xws0, int N) {
  __shared__ __align__(16) float w0l[64 * 64];
  const int t = threadIdx.x;
#pragma unroll
  for (int it = 0; it < 4; ++it) {   // W0 -> LDS before any divergent return
    int lin = (t + it * 256) * 4;
    *(float4*)&w0l[lin] = *(const float4*)&w0[lin];
  }
  __syncthreads();
  int gt = blockIdx.x * 256 + t;
  int n = __builtin_amdgcn_readfirstlane(gt >> 6);
  if (n >= N) return;
  int lane = t & 63;
  int slot = lane >> 4, kk = lane & 15;
  int cin = indeg[n], basec = offc[n];
  int cout = outdeg[n], baser = offr[n];
  float acc = 0.f;
  int c0 = (cin > 0) ? cin - 1 : 0;
  for (int i = 0; i < cin; i += 32) {
#pragma unroll
    for (int q = 0; q < 8; ++q) {
      int idx = i + q * 4 + slot;
      int eid = eidc[basec + min(idx, c0)];
      float v = ea[(size_t)eid * 16 + kk];
      acc += (idx < cin) ? v : 0.f;
    }
  }
  int r0 = (cout > 0) ? cout - 1 : 0;
  for (int i = 0; i < cout; i += 32) {
#pragma unroll
    for (int q = 0; q < 8; ++q) {
      int idx = i + q * 4 + slot;
      int eid = eidr[baser + min(idx, r0)];
      float v = ea[(size_t)eid * 16 + kk];
      acc += (idx < cout) ? v : 0.f;
    }
  }
  acc += __shfl_xor(acc, 16, 64);
  acc += __shfl_xor(acc, 32, 64);
  int j = lane;
  float v = e0[(size_t)n * 64 + j] + (float)(cin + cout) * eb[j];
#pragma unroll
  for (int k = 0; k < 16; ++k) {
    float ak = __shfl(acc, k, 64);
    v = fmaf(ak, ew[k * 64 + j], v);
  }
  float d = 1.0f / sqrtf((float)cin + 1.0f);
  if (j == 0) dis[n] = d;
  // conv0: xws0[n][j] = d * sum_k h[k] * W0[k][j], h[k] via shfl broadcast
  float a = 0.f;
#pragma unroll
  for (int k = 0; k < 64; ++k) {
    float hk = __shfl(v, k, 64);
    a = fmaf(hk, w0l[k * 64 + j], a);
  }
  xws0[(size_t)n * 64 + j] = d * a;
}

// ------- fused gather(l) + conv(l+1): 16 nodes/block, 16-deep gather -------
__global__ __launch_bounds__(256) void k_gc(
    const float* __restrict__ xin, const float* __restrict__ dis,
    const int* __restrict__ offc, const int* __restrict__ indeg,
    const int* __restrict__ srcl, const float* __restrict__ bprev,
    const float* __restrict__ wnext, float* __restrict__ hj_slice,
    float* __restrict__ xout, int N) {
  __shared__ __align__(16) float act_lds[16][64];
  __shared__ float disl[16];
  const int t = threadIdx.x;
  const int lane = t & 63;
  const int s = lane >> 4;    // sub-node within wave
  const int fg = lane & 15;   // float4 feature group
  const int nb = blockIdx.x * 16;
  const int wid = t >> 6;
  const int li = wid * 4 + s;
  int n = nb + li;
  bool ok = (n < N);
  int nn = ok ? n : (N - 1);
  int cnt = indeg[nn];
  int boff = offc[nn];
  int c0 = (cnt > 0) ? cnt - 1 : 0;
  float4 acc = *(const float4*)&xin[(size_t)nn * 64 + fg * 4];
  for (int i = 0; i < cnt; i += 16) {
    float4 v[16];
#pragma unroll
    for (int q = 0; q < 16; ++q) {
      int src = srcl[boff + min(i + q, c0)];
      v[q] = *(const float4*)&xin[(size_t)src * 64 + fg * 4];
    }
#pragma unroll
    for (int q = 0; q < 16; ++q) {
      if (i + q < cnt) {
        acc.x += v[q].x; acc.y += v[q].y; acc.z += v[q].z; acc.w += v[q].w;
      }
    }
  }
  float d = dis[nn];
  float4 bb = *(const float4*)&bprev[fg * 4];
  float4 act;
  act.x = fmaxf(fmaf(d, acc.x, bb.x), 0.f);
  act.y = fmaxf(fmaf(d, acc.y, bb.y), 0.f);
  act.z = fmaxf(fmaf(d, acc.z, bb.z), 0.f);
  act.w = fmaxf(fmaf(d, acc.w, bb.w), 0.f);
  if (ok) nt_store4(&hj_slice[(size_t)n * 192 + fg * 4], act);  // read only by pool
  *(float4*)&act_lds[li][fg * 4] = act;
  if (fg == 0) disl[li] = d;
  if (wnext == nullptr) return;
  __syncthreads();
  float wr[64];  // loaded after barrier; lifetime disjoint from gather regs
#pragma unroll
  for (int k = 0; k < 64; ++k) wr[k] = wnext[k * 64 + lane];
#pragma unroll
  for (int q = 0; q < 4; ++q) {
    int li2 = wid * 4 + q;
    int n2 = nb + li2;
    if (n2 >= N) break;
    float a = 0.f;
#pragma unroll
    for (int k4 = 0; k4 < 16; ++k4) {
      float4 av = *(const float4*)&act_lds[li2][k4 * 4];  // wave-uniform bcast
      a = fmaf(av.x, wr[k4 * 4 + 0], a);
      a = fmaf(av.y, wr[k4 * 4 + 1], a);
      a = fmaf(av.z, wr[k4 * 4 + 2], a);
      a = fmaf(av.w, wr[k4 * 4 + 3], a);
    }
    xout[(size_t)n2 * 64 + lane] = disl[li2] * a;
  }
}

// ------- mean-pool (batch sorted -> binary search) + classifier -------
__global__ __launch_bounds__(192) void k_pool(
    const float* __restrict__ hj, const int* __restrict__ batch, int N,
    const float* __restrict__ w1, const float* __restrict__ b1,
    const float* __restrict__ w2, const float* __restrict__ b2,
    float* __restrict__ out) {
  __shared__ float pl[192];
  int g = blockIdx.x;
  int t = threadIdx.x;
  int lo = 0, hi = N;
  while (lo < hi) { int m = (lo + hi) >> 1; if (batch[m] < g) lo = m + 1; else hi = m; }
  int start = lo;
  hi = N;
  while (lo < hi) { int m = (lo + hi) >> 1; if (batch[m] < g + 1) lo = m + 1; else hi = m; }
  int end = lo;
  float s = 0.f;
  for (int r = start; r < end; ++r) s += hj[(size_t)r * 192 + t];
  int cnt = end - start;
  pl[t] = s / (float)(cnt > 0 ? cnt : 1);
  __syncthreads();
  if (t < 64) {
    float val = 0.f;
    if (t < 32) {
      float z = b1[t];
#pragma unroll 8
      for (int k = 0; k < 192; ++k) z = fmaf(pl[k], w1[k * 32 + t], z);
      z = fmaxf(z, 0.f);
      val = z * w2[t];
    }
#pragma unroll
    for (int off = 16; off > 0; off >>= 1) val += __shfl_down(val, off);
    if (t == 0) out[g] = val + b2[0];
  }
}

extern "C" void kernel_launch(void* const* d_in, const int* in_sizes, int n_in,
                              void* d_out, int out_size, void* d_ws, size_t ws_size,
                              hipStream_t stream) {
  const float* x      = (const float*)d_in[0];
  const float* ea     = (const float*)d_in[1];
  const float* node_w = (const float*)d_in[2];
  const float* node_b = (const float*)d_in[3];
  const float* edge_w = (const float*)d_in[4];
  const float* edge_b = (const float*)d_in[5];
  const float* conv_w = (const float*)d_in[6];
  const float* conv_b = (const float*)d_in[7];
  const float* w1     = (const float*)d_in[8];
  const float* b1     = (const float*)d_in[9];
  const float* w2     = (const float*)d_in[10];
  const float* b2     = (const float*)d_in[11];
  const int*   ei     = (const int*)d_in[12];
  const int*   batch  = (const int*)d_in[13];

  const int N = in_sizes[0] / 128;
  const int E = in_sizes[12] / 2;
  const int G = out_size;
  const int* erow = ei;
  const int* ecol = ei + E;

  float* ws = (float*)d_ws;
  size_t o = 0;
  float* e0    = ws + o; o += (size_t)N * 64;
  float* xwsA  = ws + o; o += (size_t)N * 64;
  float* xwsB  = ws + o; o += (size_t)N * 64;
  float* hj    = ws + o; o += (size_t)N * 192;  // build scratch aliases its head
  float* dis   = ws + o; o += N;
  int* indeg   = (int*)(ws + o); o += N;
  int* outdeg  = (int*)(ws + o); o += N;
  int* offc    = (int*)(ws + o); o += N;
  int* offr    = (int*)(ws + o); o += N;
  int* srcl    = (int*)(ws + o); o += E;
  int* eidc    = (int*)(ws + o); o += E;
  int* eidr    = (int*)(ws + o); o += E;

  const int NB = (N + 255) >> 8;              // buckets (<=512)
  const int NBLK = (E + EPB - 1) / EPB;       // binning blocks
  // aliases onto hj (all dead before first k_gc writes hj):
  unsigned long long* tmpc = (unsigned long long*)hj;          // E*8B
  unsigned int* tmpr = (unsigned int*)(hj + (size_t)2 * E);    // E*4B
  int* matTc = (int*)(hj + (size_t)3 * E);                     // NB*NBLK
  int* matTr = matTc + (size_t)NB * NBLK;
  int* totc  = matTr + (size_t)NB * NBLK;
  int* startc = totc + NB;
  int* totr  = startc + NB;
  int* startr = totr + NB;
  float* out = (float*)d_out;

  dim3 b256(256);
  const int NT = (N + 63) / 64;

  k_embed<<<NT, b256, 0, stream>>>(x, node_w, node_b, e0, N);
  k_hist<<<NBLK, b256, 0, stream>>>(erow, ecol, matTc, matTr, E, NB, NBLK);
  kBscan<<<2 * NB, b256, 0, stream>>>(matTc, matTr, totc, totr, NB, NBLK);
  kB2<<<2, dim3(512), 0, stream>>>(totc, totr, startc, startr, NB);
  k_scat<<<NBLK, b256, 0, stream>>>(erow, ecol, matTc, matTr, startc, startr,
                                    tmpc, tmpr, E, NB, NBLK);
  k_bplace<<<2 * NB, b256, 0, stream>>>(tmpc, tmpr, startc, startr, totc, totr,
                                        indeg, outdeg, offc, offr,
                                        srcl, eidc, eidr, N, NB);
  // edge embed + conv0 -> xwsA (h never hits memory)
  k_eembed<<<((size_t)N * 64 + 255) / 256, b256, 0, stream>>>(
      e0, ea, eidc, eidr, offc, indeg, offr, outdeg,
      edge_w, edge_b, conv_w, dis, xwsA, N);
  // gather0 + conv1 -> xwsB ; gather1 + conv2 -> xwsA ; gather2 only
  k_gc<<<(N + 15) / 16, b256, 0, stream>>>(
      xwsA, dis, offc, indeg, srcl, conv_b,
      conv_w + (size_t)1 * 64 * 64, hj, xwsB, N);
  k_gc<<<(N + 15) / 16, b256, 0, stream>>>(
      xwsB, dis, offc, indeg, srcl, conv_b + 64,
      conv_w + (size_t)2 * 64 * 64, hj + 64, xwsA, N);
  k_gc<<<(N + 15) / 16, b256, 0, stream>>>(
      xwsA, dis, offc, indeg, srcl, conv_b + 128,
      nullptr, hj + 128, nullptr, N);
  k_pool<<<G, dim3(192), 0, stream>>>(hj, batch, N, w1, b1, w2, b2, out);
}

// Round 14
// 438.588 us; speedup vs baseline: 1.1358x; 1.1358x over previous
//
#include <hip/hip_runtime.h>
#include <math.h>

// GraphCNN v14 == v12 (best, 438us). v13's conv0-fold into k_eembed reverted:
//  shfl-broadcast conv doubled per-node issue count (64 shfl+64 LDS+64 fma per
//  lane) on a BW-pinned kernel -> 78->157us. v12 components at their measured
//  pattern ceilings: eembed 2.58 TB/s random-line, k_gc BW-bound (16-deep probe
//  +0%), build contention-free.
//  Assumes N <= 131072 (NB <= 512), E < 2^24, N < 2^17.

#define EPB 4096  // edges per binning block

// ------- node embed: out[n][j] = sum_k x[n][k] w[k][j] + b[j]  (K=128) -------
__global__ __launch_bounds__(256) void k_embed(
    const float* __restrict__ x, const float* __restrict__ w,
    const float* __restrict__ b, float* __restrict__ out, int N) {
  __shared__ __align__(16) float rl[64 * 128];
  const int t = threadIdx.x;
  const int j = t & 63;
  const int wv = t >> 6;
  const int base = blockIdx.x * 64;
  float wr[128];
#pragma unroll
  for (int k = 0; k < 128; ++k) wr[k] = w[k * 64 + j];
  const float bj = b[j];
#pragma unroll
  for (int it = 0; it < 8; ++it) {
    int lin = (t + it * 256) * 4;
    int r = lin >> 7, c = lin & 127;
    int row = base + r;
    float4 v = (row < N) ? *(const float4*)&x[(size_t)row * 128 + c]
                         : make_float4(0.f, 0.f, 0.f, 0.f);
    *(float4*)&rl[lin] = v;
  }
  __syncthreads();
  for (int r = wv; r < 64; r += 4) {
    int row = base + r;
    if (row >= N) break;
    float acc = bj;
#pragma unroll
    for (int k4 = 0; k4 < 32; ++k4) {
      float4 a = *(const float4*)&rl[r * 128 + k4 * 4];
      acc = fmaf(a.x, wr[k4 * 4 + 0], acc);
      acc = fmaf(a.y, wr[k4 * 4 + 1], acc);
      acc = fmaf(a.z, wr[k4 * 4 + 2], acc);
      acc = fmaf(a.w, wr[k4 * 4 + 3], acc);
    }
    out[(size_t)row * 64 + j] = acc;
  }
}

// ------- conv GEMM (layer 0): xws[n][j] = dis[n]*sum_k h[n][k] w[k][j] -------
__global__ __launch_bounds__(256) void k_conv(
    const float* __restrict__ hin, const float* __restrict__ w,
    const float* __restrict__ dis, float* __restrict__ xws, int N) {
  __shared__ __align__(16) float rl[64 * 64];
  const int t = threadIdx.x;
  const int j = t & 63;
  const int wv = t >> 6;
  const int base = blockIdx.x * 64;
  float wr[64];
#pragma unroll
  for (int k = 0; k < 64; ++k) wr[k] = w[k * 64 + j];
#pragma unroll
  for (int it = 0; it < 4; ++it) {
    int lin = (t + it * 256) * 4;
    int r = lin >> 6, c = lin & 63;
    int row = base + r;
    float4 v = (row < N) ? *(const float4*)&hin[(size_t)row * 64 + c]
                         : make_float4(0.f, 0.f, 0.f, 0.f);
    *(float4*)&rl[lin] = v;
  }
  __syncthreads();
  for (int r = wv; r < 64; r += 4) {
    int row = base + r;
    if (row >= N) break;
    float acc = 0.f;
#pragma unroll
    for (int k4 = 0; k4 < 16; ++k4) {
      float4 a = *(const float4*)&rl[r * 64 + k4 * 4];
      acc = fmaf(a.x, wr[k4 * 4 + 0], acc);
      acc = fmaf(a.y, wr[k4 * 4 + 1], acc);
      acc = fmaf(a.z, wr[k4 * 4 + 2], acc);
      acc = fmaf(a.w, wr[k4 * 4 + 3], acc);
    }
    xws[(size_t)row * 64 + j] = dis[row] * acc;
  }
}

// ------- per-block bucket histograms, bucket-major: matT[bucket*NBLK + blk] -------
__global__ __launch_bounds__(256) void k_hist(
    const int* __restrict__ erow, const int* __restrict__ ecol,
    int* __restrict__ matTc, int* __restrict__ matTr, int E, int NB, int NBLK) {
  __shared__ int hc[512], hr[512];
  int b = blockIdx.x, t = threadIdx.x;
  for (int i = t; i < NB; i += 256) { hc[i] = 0; hr[i] = 0; }
  __syncthreads();
  int e0 = b * EPB;
#pragma unroll
  for (int q = 0; q < 16; ++q) {
    int e = e0 + q * 256 + t;
    if (e < E) {
      atomicAdd(&hc[ecol[e] >> 8], 1);
      atomicAdd(&hr[erow[e] >> 8], 1);
    }
  }
  __syncthreads();
  for (int i = t; i < NB; i += 256) {
    matTc[(size_t)i * NBLK + b] = hc[i];
    matTr[(size_t)i * NBLK + b] = hr[i];
  }
}

// ------- per-bucket scan over blocks; grid = 2*NB (c then r) -------
__global__ __launch_bounds__(256) void kBscan(
    int* __restrict__ matTc, int* __restrict__ matTr,
    int* __restrict__ totc, int* __restrict__ totr, int NB, int NBLK) {
  __shared__ int sc[256];
  int bi = blockIdx.x, t = threadIdx.x;
  int side = (bi >= NB) ? 1 : 0;
  int i = bi - side * NB;
  int* row = (side ? matTr : matTc) + (size_t)i * NBLK;
  int* tot = side ? totr : totc;
  int e0 = (2 * t < NBLK) ? row[2 * t] : 0;
  int e1 = (2 * t + 1 < NBLK) ? row[2 * t + 1] : 0;
  int s = e0 + e1;
  sc[t] = s;
  __syncthreads();
  for (int d = 1; d < 256; d <<= 1) {
    int x = (t >= d) ? sc[t - d] : 0;
    __syncthreads();
    sc[t] += x;
    __syncthreads();
  }
  int excl = sc[t] - s;
  if (2 * t < NBLK) row[2 * t] = excl;
  if (2 * t + 1 < NBLK) row[2 * t + 1] = excl + e0;
  if (t == 255) tot[i] = sc[255];
}

// ------- exclusive scan of bucket totals -> starts; grid = 2 -------
__global__ __launch_bounds__(512) void kB2(
    const int* __restrict__ totc, const int* __restrict__ totr,
    int* __restrict__ startc, int* __restrict__ startr, int NB) {
  __shared__ int sc[512];
  int t = threadIdx.x;
  const int* tot = blockIdx.x ? totr : totc;
  int* start = blockIdx.x ? startr : startc;
  int s = (t < NB) ? tot[t] : 0;
  sc[t] = s;
  __syncthreads();
  for (int d = 1; d < 512; d <<= 1) {
    int x = (t >= d) ? sc[t - d] : 0;
    __syncthreads();
    sc[t] += x;
    __syncthreads();
  }
  if (t < NB) start[t] = sc[t] - s;
}

// ------- scatter into bucket regions; LDS cursors, no global atomics -------
__global__ __launch_bounds__(256) void k_scat(
    const int* __restrict__ erow, const int* __restrict__ ecol,
    const int* __restrict__ matTc, const int* __restrict__ matTr,
    const int* __restrict__ startc, const int* __restrict__ startr,
    unsigned long long* __restrict__ tmpc, unsigned int* __restrict__ tmpr,
    int E, int NB, int NBLK) {
  __shared__ int curc[512], curr[512];
  int b = blockIdx.x, t = threadIdx.x;
  for (int i = t; i < NB; i += 256) {
    curc[i] = startc[i] + matTc[(size_t)i * NBLK + b];
    curr[i] = startr[i] + matTr[(size_t)i * NBLK + b];
  }
  __syncthreads();
  int e0 = b * EPB;
#pragma unroll
  for (int q = 0; q < 16; ++q) {
    int e = e0 + q * 256 + t;
    if (e < E) {
      int r = erow[e], c = ecol[e];
      int pc = atomicAdd(&curc[c >> 8], 1);
      tmpc[pc] = (unsigned long long)(c & 255) |
                 ((unsigned long long)r << 8) |
                 ((unsigned long long)e << 25);
      int pr = atomicAdd(&curr[r >> 8], 1);
      tmpr[pr] = ((unsigned int)e << 8) | (unsigned int)(r & 255);
    }
  }
}

// ------- merged: per-bucket degree + CSR offset + placement; grid = 2*NB -------
__global__ __launch_bounds__(256) void k_bplace(
    const unsigned long long* __restrict__ tmpc,
    const unsigned int* __restrict__ tmpr,
    const int* __restrict__ startc, const int* __restrict__ startr,
    const int* __restrict__ totc, const int* __restrict__ totr,
    int* __restrict__ indeg, int* __restrict__ outdeg,
    int* __restrict__ offc, int* __restrict__ offr,
    int* __restrict__ srcl, int* __restrict__ eidc, int* __restrict__ eidr,
    int N, int NB) {
  __shared__ int h[256], sc[256];
  int bi = blockIdx.x, t = threadIdx.x;
  int side = (bi >= NB) ? 1 : 0;
  int b = bi - side * NB;
  h[t] = 0;
  __syncthreads();
  int bstart = side ? startr[b] : startc[b];
  int cnt = side ? totr[b] : totc[b];
  if (side) {
    for (int i = t; i < cnt; i += 256)
      atomicAdd(&h[(int)(tmpr[bstart + i] & 255)], 1);
  } else {
    for (int i = t; i < cnt; i += 256)
      atomicAdd(&h[(int)(tmpc[bstart + i] & 255)], 1);
  }
  __syncthreads();
  int s = h[t];
  sc[t] = s;
  __syncthreads();
  for (int d = 1; d < 256; d <<= 1) {
    int x = (t >= d) ? sc[t - d] : 0;
    __syncthreads();
    sc[t] += x;
    __syncthreads();
  }
  int n = (b << 8) + t;
  int myoff = bstart + sc[t] - s;
  if (n < N) {
    if (side) { outdeg[n] = s; offr[n] = myoff; }
    else      { indeg[n] = s;  offc[n] = myoff; }
  }
  h[t] = myoff;  // reuse as place cursor
  __syncthreads();
  if (side) {
    for (int i = t; i < cnt; i += 256) {
      unsigned int v = tmpr[bstart + i];   // L2-warm
      int p = atomicAdd(&h[(int)(v & 255)], 1);
      eidr[p] = (int)(v >> 8);
    }
  } else {
    for (int i = t; i < cnt; i += 256) {
      unsigned long long v = tmpc[bstart + i];
      int p = atomicAdd(&h[(int)(v & 255)], 1);
      srcl[p] = (int)((v >> 8) & 0x1FFFF);
      eidc[p] = (int)(v >> 25);
    }
  }
}

// ------- fused edge embed: dual gather (32-deep) + 16->64 GEMM + dis -------
__global__ __launch_bounds__(256) void k_eembed(
    const float* __restrict__ ea, const int* __restrict__ eidc,
    const int* __restrict__ eidr, const int* __restrict__ offc,
    const int* __restrict__ indeg, const int* __restrict__ offr,
    const int* __restrict__ outdeg, const float* __restrict__ ew,
    const float* __restrict__ eb, float* h0, float* __restrict__ dis, int N) {
  int t = blockIdx.x * 256 + threadIdx.x;
  int n = __builtin_amdgcn_readfirstlane(t >> 6);
  if (n >= N) return;
  int lane = threadIdx.x & 63;
  int slot = lane >> 4, kk = lane & 15;
  int cin = indeg[n], basec = offc[n];
  int cout = outdeg[n], baser = offr[n];
  float acc = 0.f;
  int c0 = (cin > 0) ? cin - 1 : 0;
  for (int i = 0; i < cin; i += 32) {
#pragma unroll
    for (int q = 0; q < 8; ++q) {
      int idx = i + q * 4 + slot;
      int eid = eidc[basec + min(idx, c0)];
      float v = ea[(size_t)eid * 16 + kk];
      acc += (idx < cin) ? v : 0.f;
    }
  }
  int r0 = (cout > 0) ? cout - 1 : 0;
  for (int i = 0; i < cout; i += 32) {
#pragma unroll
    for (int q = 0; q < 8; ++q) {
      int idx = i + q * 4 + slot;
      int eid = eidr[baser + min(idx, r0)];
      float v = ea[(size_t)eid * 16 + kk];
      acc += (idx < cout) ? v : 0.f;
    }
  }
  acc += __shfl_xor(acc, 16, 64);
  acc += __shfl_xor(acc, 32, 64);
  int j = lane;
  float v = h0[(size_t)n * 64 + j] + (float)(cin + cout) * eb[j];
#pragma unroll
  for (int k = 0; k < 16; ++k) {
    float ak = __shfl(acc, k, 64);
    v = fmaf(ak, ew[k * 64 + j], v);
  }
  h0[(size_t)n * 64 + j] = v;
  if (j == 0) dis[n] = 1.0f / sqrtf((float)cin + 1.0f);
}

// ------- fused gather(l) + conv(l+1): 16 nodes/block, 16-deep gather -------
__global__ __launch_bounds__(256) void k_gc(
    const float* __restrict__ xin, const float* __restrict__ dis,
    const int* __restrict__ offc, const int* __restrict__ indeg,
    const int* __restrict__ srcl, const float* __restrict__ bprev,
    const float* __restrict__ wnext, float* __restrict__ hj_slice,
    float* __restrict__ xout, int N) {
  __shared__ __align__(16) float act_lds[16][64];
  __shared__ float disl[16];
  const int t = threadIdx.x;
  const int lane = t & 63;
  const int s = lane >> 4;    // sub-node within wave
  const int fg = lane & 15;   // float4 feature group
  const int nb = blockIdx.x * 16;
  const int wid = t >> 6;
  const int li = wid * 4 + s;
  int n = nb + li;
  bool ok = (n < N);
  int nn = ok ? n : (N - 1);
  int cnt = indeg[nn];
  int boff = offc[nn];
  int c0 = (cnt > 0) ? cnt - 1 : 0;
  float4 acc = *(const float4*)&xin[(size_t)nn * 64 + fg * 4];
  for (int i = 0; i < cnt; i += 16) {
    float4 v[16];
#pragma unroll
    for (int q = 0; q < 16; ++q) {
      int src = srcl[boff + min(i + q, c0)];
      v[q] = *(const float4*)&xin[(size_t)src * 64 + fg * 4];
    }
#pragma unroll
    for (int q = 0; q < 16; ++q) {
      if (i + q < cnt) {
        acc.x += v[q].x; acc.y += v[q].y; acc.z += v[q].z; acc.w += v[q].w;
      }
    }
  }
  float d = dis[nn];
  float4 bb = *(const float4*)&bprev[fg * 4];
  float4 act;
  act.x = fmaxf(fmaf(d, acc.x, bb.x), 0.f);
  act.y = fmaxf(fmaf(d, acc.y, bb.y), 0.f);
  act.z = fmaxf(fmaf(d, acc.z, bb.z), 0.f);
  act.w = fmaxf(fmaf(d, acc.w, bb.w), 0.f);
  if (ok) *(float4*)&hj_slice[(size_t)n * 192 + fg * 4] = act;
  *(float4*)&act_lds[li][fg * 4] = act;
  if (fg == 0) disl[li] = d;
  if (wnext == nullptr) return;
  __syncthreads();
  float wr[64];  // loaded after barrier; lifetime disjoint from gather regs
#pragma unroll
  for (int k = 0; k < 64; ++k) wr[k] = wnext[k * 64 + lane];
#pragma unroll
  for (int q = 0; q < 4; ++q) {
    int li2 = wid * 4 + q;
    int n2 = nb + li2;
    if (n2 >= N) break;
    float a = 0.f;
#pragma unroll
    for (int k4 = 0; k4 < 16; ++k4) {
      float4 av = *(const float4*)&act_lds[li2][k4 * 4];  // wave-uniform bcast
      a = fmaf(av.x, wr[k4 * 4 + 0], a);
      a = fmaf(av.y, wr[k4 * 4 + 1], a);
      a = fmaf(av.z, wr[k4 * 4 + 2], a);
      a = fmaf(av.w, wr[k4 * 4 + 3], a);
    }
    xout[(size_t)n2 * 64 + lane] = disl[li2] * a;
  }
}

// ------- mean-pool (batch sorted -> binary search) + classifier -------
__global__ __launch_bounds__(192) void k_pool(
    const float* __restrict__ hj, const int* __restrict__ batch, int N,
    const float* __restrict__ w1, const float* __restrict__ b1,
    const float* __restrict__ w2, const float* __restrict__ b2,
    float* __restrict__ out) {
  __shared__ float pl[192];
  int g = blockIdx.x;
  int t = threadIdx.x;
  int lo = 0, hi = N;
  while (lo < hi) { int m = (lo + hi) >> 1; if (batch[m] < g) lo = m + 1; else hi = m; }
  int start = lo;
  hi = N;
  while (lo < hi) { int m = (lo + hi) >> 1; if (batch[m] < g + 1) lo = m + 1; else hi = m; }
  int end = lo;
  float s = 0.f;
  for (int r = start; r < end; ++r) s += hj[(size_t)r * 192 + t];
  int cnt = end - start;
  pl[t] = s / (float)(cnt > 0 ? cnt : 1);
  __syncthreads();
  if (t < 64) {
    float val = 0.f;
    if (t < 32) {
      float z = b1[t];
#pragma unroll 8
      for (int k = 0; k < 192; ++k) z = fmaf(pl[k], w1[k * 32 + t], z);
      z = fmaxf(z, 0.f);
      val = z * w2[t];
    }
#pragma unroll
    for (int off = 16; off > 0; off >>= 1) val += __shfl_down(val, off);
    if (t == 0) out[g] = val + b2[0];
  }
}

extern "C" void kernel_launch(void* const* d_in, const int* in_sizes, int n_in,
                              void* d_out, int out_size, void* d_ws, size_t ws_size,
                              hipStream_t stream) {
  const float* x      = (const float*)d_in[0];
  const float* ea     = (const float*)d_in[1];
  const float* node_w = (const float*)d_in[2];
  const float* node_b = (const float*)d_in[3];
  const float* edge_w = (const float*)d_in[4];
  const float* edge_b = (const float*)d_in[5];
  const float* conv_w = (const float*)d_in[6];
  const float* conv_b = (const float*)d_in[7];
  const float* w1     = (const float*)d_in[8];
  const float* b1     = (const float*)d_in[9];
  const float* w2     = (const float*)d_in[10];
  const float* b2     = (const float*)d_in[11];
  const int*   ei     = (const int*)d_in[12];
  const int*   batch  = (const int*)d_in[13];

  const int N = in_sizes[0] / 128;
  const int E = in_sizes[12] / 2;
  const int G = out_size;
  const int* erow = ei;
  const int* ecol = ei + E;

  float* ws = (float*)d_ws;
  size_t o = 0;
  float* h0    = ws + o; o += (size_t)N * 64;
  float* xwsA  = ws + o; o += (size_t)N * 64;
  float* xwsB  = ws + o; o += (size_t)N * 64;
  float* hj    = ws + o; o += (size_t)N * 192;  // build scratch aliases its head
  float* dis   = ws + o; o += N;
  int* indeg   = (int*)(ws + o); o += N;
  int* outdeg  = (int*)(ws + o); o += N;
  int* offc    = (int*)(ws + o); o += N;
  int* offr    = (int*)(ws + o); o += N;
  int* srcl    = (int*)(ws + o); o += E;
  int* eidc    = (int*)(ws + o); o += E;
  int* eidr    = (int*)(ws + o); o += E;

  const int NB = (N + 255) >> 8;              // buckets (<=512)
  const int NBLK = (E + EPB - 1) / EPB;       // binning blocks
  // aliases onto hj (all dead before first k_gc writes hj):
  unsigned long long* tmpc = (unsigned long long*)hj;          // E*8B
  unsigned int* tmpr = (unsigned int*)(hj + (size_t)2 * E);    // E*4B
  int* matTc = (int*)(hj + (size_t)3 * E);                     // NB*NBLK
  int* matTr = matTc + (size_t)NB * NBLK;
  int* totc  = matTr + (size_t)NB * NBLK;
  int* startc = totc + NB;
  int* totr  = startc + NB;
  int* startr = totr + NB;
  float* out = (float*)d_out;

  dim3 b256(256);
  const int NT = (N + 63) / 64;

  k_embed<<<NT, b256, 0, stream>>>(x, node_w, node_b, h0, N);
  k_hist<<<NBLK, b256, 0, stream>>>(erow, ecol, matTc, matTr, E, NB, NBLK);
  kBscan<<<2 * NB, b256, 0, stream>>>(matTc, matTr, totc, totr, NB, NBLK);
  kB2<<<2, dim3(512), 0, stream>>>(totc, totr, startc, startr, NB);
  k_scat<<<NBLK, b256, 0, stream>>>(erow, ecol, matTc, matTr, startc, startr,
                                    tmpc, tmpr, E, NB, NBLK);
  k_bplace<<<2 * NB, b256, 0, stream>>>(tmpc, tmpr, startc, startr, totc, totr,
                                        indeg, outdeg, offc, offr,
                                        srcl, eidc, eidr, N, NB);
  k_eembed<<<((size_t)N * 64 + 255) / 256, b256, 0, stream>>>(
      ea, eidc, eidr, offc, indeg, offr, outdeg, edge_w, edge_b, h0, dis, N);
  k_conv<<<NT, b256, 0, stream>>>(h0, conv_w, dis, xwsA, N);
  // gather0 + conv1 -> xwsB ; gather1 + conv2 -> xwsA ; gather2 only
  k_gc<<<(N + 15) / 16, b256, 0, stream>>>(
      xwsA, dis, offc, indeg, srcl, conv_b,
      conv_w + (size_t)1 * 64 * 64, hj, xwsB, N);
  k_gc<<<(N + 15) / 16, b256, 0, stream>>>(
      xwsB, dis, offc, indeg, srcl, conv_b + 64,
      conv_w + (size_t)2 * 64 * 64, hj + 64, xwsA, N);
  k_gc<<<(N + 15) / 16, b256, 0, stream>>>(
      xwsA, dis, offc, indeg, srcl, conv_b + 128,
      nullptr, hj + 128, nullptr, N);
  k_pool<<<G, dim3(192), 0, stream>>>(hj, batch, N, w1, b1, w2, b2, out);
}